// Round 14
// baseline (955.805 us; speedup 1.0000x reference)
//
#include <hip/hip_runtime.h>
#include <hip/hip_fp16.h>
#include <stdint.h>

// Bidirectional LSTM: N=1024, T=512, H=128; enc 2->128->128; dec 256->128->1.
// fp16 MFMA (fp32 accum). ws = 256 MiB:
//   bufA 128MiB: feat -> overwritten in place with relu(h_fw)   [t][n][128] fp16
//   bufB 128MiB: feat -> overwritten in place with relu(h_bw)   [t][n][128] fp16
// Round-14 LSTM: 256 blocks x 1024 thr (16 waves -> 4 waves/SIMD, vs r7's 2).
// Wave w: dims [16d,16d+16) (d=w&7), gates {i,f} if gp=w>>3==0 else {g,o};
// 2 gate-tiles, 16 MFMA/step, weights 64 VGPR. gp1 hands g,o to gp0 via LDS;
// gp0 does elementwise (halved per wave). Barrier-bounded regions force
// cross-wave MFMA/VALU overlap (gp1's next-step feat-MFMAs run in the A-B
// window against gp0's elementwise) — compiler cannot reorder across
// __syncthreads, unlike r8-r11's failed intra-wave attempts.
// Per-value FP op order identical to r7 -> absmax oracle 2.441406e-4.

#define TN 512
#define NB 1024

typedef __attribute__((ext_vector_type(8))) _Float16 f16x8;
typedef __attribute__((ext_vector_type(4))) float f32x4;

#define MFMA16(a,b,c) __builtin_amdgcn_mfma_f32_16x16x32_f16(a,b,c,0,0,0)
#define RCP(x) __builtin_amdgcn_rcpf(x)

__device__ __forceinline__ f16x8 cvt_frag(const float* p){
  f32x4 a = *(const f32x4*)p;
  f32x4 b = *(const f32x4*)(p+4);
  f16x8 h;
  h[0]=(_Float16)a[0]; h[1]=(_Float16)a[1]; h[2]=(_Float16)a[2]; h[3]=(_Float16)a[3];
  h[4]=(_Float16)b[0]; h[5]=(_Float16)b[1]; h[6]=(_Float16)b[2]; h[7]=(_Float16)b[3];
  return h;
}

__device__ __forceinline__ unsigned short f2h(float f){
  return __half_as_ushort(__float2half(f));
}

// ---------------- K0: encoder -> feat fp16 [t][n][128], written to BOTH copies ----------------
__global__ __launch_bounds__(256) void enc_kernel(
    const float* __restrict__ x,  const float* __restrict__ e1w,
    const float* __restrict__ e1b,const float* __restrict__ e2w,
    const float* __restrict__ e2b,
    unsigned short* __restrict__ featA, unsigned short* __restrict__ featB)
{
  __shared__ float xs[64][2];
  __shared__ unsigned int A32[64][68];   // r1 fp16 pairs, row stride 272B
  int tid = threadIdx.x;
  long rowbase = (long)blockIdx.x * 64;  // row = t*1024 + n
  if (tid < 128){
    int i = tid >> 1, cc = tid & 1;
    long row = rowbase + i;
    int t = (int)(row >> 10), n = (int)(row & 1023);
    xs[i][cc] = x[((size_t)n * TN + t) * 2 + cc];
  }
  int w4 = tid >> 6, lane = tid & 63, lq = lane >> 4, lr = lane & 15;
  f16x8 Bf[2][4];
  float b2v[2];
  #pragma unroll
  for (int nt2 = 0; nt2 < 2; nt2++){
    int col = (w4*2 + nt2)*16 + lr;
    b2v[nt2] = e2b[col];
    #pragma unroll
    for (int ks = 0; ks < 4; ks++)
      Bf[nt2][ks] = cvt_frag(e2w + col*128 + ks*32 + lq*8);
  }
  int q = tid >> 6, dp = tid & 63;
  float w00 = e1w[4*dp], w01 = e1w[4*dp+1], w10 = e1w[4*dp+2], w11 = e1w[4*dp+3];
  float b0 = e1b[2*dp], b1 = e1b[2*dp+1];
  __syncthreads();
  #pragma unroll
  for (int rr = 0; rr < 16; rr++){
    int r = q*16 + rr;
    float x0 = xs[r][0], x1 = xs[r][1];
    float v0 = fmaxf(w00*x0 + w01*x1 + b0, 0.f);
    float v1 = fmaxf(w10*x0 + w11*x1 + b1, 0.f);
    A32[r][dp] = (unsigned int)f2h(v0) | ((unsigned int)f2h(v1) << 16);
  }
  __syncthreads();
  #pragma unroll
  for (int Mt = 0; Mt < 4; Mt++){
    f16x8 ah[4];
    #pragma unroll
    for (int ks = 0; ks < 4; ks++)
      ah[ks] = *(const f16x8*)((const unsigned short*)&A32[Mt*16+lr][0] + ks*32 + lq*8);
    f32x4 acc0 = {0.f,0.f,0.f,0.f}, acc1 = {0.f,0.f,0.f,0.f};
    #pragma unroll
    for (int ks = 0; ks < 4; ks++){
      acc0 = MFMA16(ah[ks], Bf[0][ks], acc0);
      acc1 = MFMA16(ah[ks], Bf[1][ks], acc1);
    }
    #pragma unroll
    for (int r = 0; r < 4; r++){
      size_t row = (size_t)(rowbase + Mt*16 + lq*4 + r);
      unsigned short v0 = f2h(acc0[r] + b2v[0]);
      unsigned short v1 = f2h(acc1[r] + b2v[1]);
      featA[row*128 + (w4*2+0)*16 + lr] = v0;
      featA[row*128 + (w4*2+1)*16 + lr] = v1;
      featB[row*128 + (w4*2+0)*16 + lr] = v0;
      featB[row*128 + (w4*2+1)*16 + lr] = v1;
    }
  }
}

// ---------------- K1: persistent bidirectional LSTM (16-wave, gate-split) ----------------
// STEP(P, ACCC, ACCN): ACCC holds feat(s)-part on entry; add h(s); gp1 hands
// g,o to gp0; gp0 elementwise in A-B window while gp1 computes feat(s+1).
#define LSTM_STEP(P, ACCC, ACCN) do { \
    f16x8 ah[4]; \
    _Pragma("unroll") \
    for (int ks = 0; ks < 4; ks++) ah[ks] = *(const f16x8*)&hbS[P][smr][ks*32 + lq*8]; \
    _Pragma("unroll") \
    for (int ks = 0; ks < 4; ks++){ \
      ACCC[0] = MFMA16(ah[ks], wg[0][4+ks], ACCC[0]); \
      ACCC[1] = MFMA16(ah[ks], wg[1][4+ks], ACCC[1]); \
    } \
    if (gp == 0){ \
      ACCN[0] = MFMA16(*(const f16x8*)&pf[0], wg[0][0], zero4); \
      ACCN[1] = MFMA16(*(const f16x8*)&pf[0], wg[1][0], zero4); \
      _Pragma("unroll") \
      for (int ks = 1; ks < 4; ks++){ \
        ACCN[0] = MFMA16(*(const f16x8*)&pf[ks], wg[0][ks], ACCN[0]); \
        ACCN[1] = MFMA16(*(const f16x8*)&pf[ks], wg[1][ks], ACCN[1]); \
      } \
      _Pragma("unroll") \
      for (int ks = 0; ks < 4; ks++) pf[ks] = *(const uint4*)(fpp + ks*32); \
      fpp += dstep; \
    } else { \
      gw[d][0][lane] = ACCC[0][0]; \
      gw[d][1][lane] = ACCC[1][0]; \
      gw[d][2][lane] = ACCC[0][1]; \
      gw[d][3][lane] = ACCC[1][1]; \
    } \
    __syncthreads();   /* A: g,o visible; hbS[P] reads done */ \
    if (gp == 0){ \
      float gv0 = gw[d][0][lane], ov0 = gw[d][1][lane]; \
      float gv1 = gw[d][2][lane], ov1 = gw[d][3][lane]; \
      float iv0 = ACCC[0][0], fv0 = ACCC[1][0]; \
      float iv1 = ACCC[0][1], fv1 = ACCC[1][1]; \
      float si0 = RCP(1.f + __expf(-iv0)); \
      float sf0 = RCP(1.f + __expf(-fv0)); \
      float so0 = RCP(1.f + __expf(-ov0)); \
      float tg0 = 1.f - 2.f*RCP(__expf(2.f*gv0) + 1.f); \
      float si1 = RCP(1.f + __expf(-iv1)); \
      float sf1 = RCP(1.f + __expf(-fv1)); \
      float so1 = RCP(1.f + __expf(-ov1)); \
      float tg1 = 1.f - 2.f*RCP(__expf(2.f*gv1) + 1.f); \
      c[0] = sf0*c[0] + si0*tg0; \
      c[1] = sf1*c[1] + si1*tg1; \
      float tc0 = 1.f - 2.f*RCP(__expf(2.f*c[0]) + 1.f); \
      float tc1 = 1.f - 2.f*RCP(__expf(2.f*c[1]) + 1.f); \
      float hv0 = so0*tc0, hv1 = so1*tc1; \
      unsigned short hh0 = f2h(hv0), hh1 = f2h(hv1); \
      hbS[(P)^1][lq*2+0][d*16 + lr] = hh0; \
      hbS[(P)^1][lq*2+1][d*16 + lr] = hh1; \
      op[0]   = (hv0 > 0.f) ? hh0 : (unsigned short)0; \
      op[128] = (hv1 > 0.f) ? hh1 : (unsigned short)0; \
      op += dstep; \
    } else { \
      ACCN[0] = MFMA16(*(const f16x8*)&pf[0], wg[0][0], zero4); \
      ACCN[1] = MFMA16(*(const f16x8*)&pf[0], wg[1][0], zero4); \
      _Pragma("unroll") \
      for (int ks = 1; ks < 4; ks++){ \
        ACCN[0] = MFMA16(*(const f16x8*)&pf[ks], wg[0][ks], ACCN[0]); \
        ACCN[1] = MFMA16(*(const f16x8*)&pf[ks], wg[1][ks], ACCN[1]); \
      } \
      _Pragma("unroll") \
      for (int ks = 0; ks < 4; ks++) pf[ks] = *(const uint4*)(fpp + ks*32); \
      fpp += dstep; \
    } \
    __syncthreads();   /* B: h(s) ready; gw reads done */ \
  } while(0)

__global__ __launch_bounds__(1024, 4) void lstm_kernel(
    unsigned short* bufA, unsigned short* bufB,
    const float* __restrict__ wih, const float* __restrict__ whh)
{
  __shared__ __align__(16) unsigned short hbS[2][8][132];   // 4224 B, ~2-way banks
  __shared__ float gw[8][4][65];                            // 8320 B, conflict-free b32
  int tid = threadIdx.x, b = blockIdx.x;
  int dir = b >> 7, n0 = (b & 127) << 3;
  int w = tid >> 6, lane = tid & 63, lq = lane >> 4, lr = lane & 15;
  int d = w & 7, gp = w >> 3;
  unsigned short* buf = dir ? bufB : bufA;
  long dstep = dir ? -(long)(NB*128) : (long)(NB*128);
  long t0 = dir ? (TN-1) : 0;
  const f32x4 zero4 = {0.f, 0.f, 0.f, 0.f};

  // resident weights: 2 gate-tiles (G = gp*2+G2), ks<4 = w_ih, ks>=4 = w_hh
  f16x8 wg[2][8];
  #pragma unroll
  for (int G2 = 0; G2 < 2; G2++){
    int gate = (gp*2 + G2)*128 + d*16 + lr;
    #pragma unroll
    for (int ks = 0; ks < 8; ks++){
      const float* src = (ks < 4) ? (wih + (size_t)gate*128 + ks*32 + lq*8)
                                  : (whh + (size_t)gate*128 + (ks-4)*32 + lq*8);
      wg[G2][ks] = cvt_frag(src);
    }
  }

  for (int i = tid; i < 1056; i += 1024) ((unsigned int*)hbS)[i] = 0u;

  int smr = ((lr >> 2) << 1) | (lr & 1);   // A-row lr -> chain
  float c[2] = {0.f, 0.f};

  const unsigned short* fpp = buf + ((size_t)t0*NB + n0 + smr)*128 + lq*8;
  uint4 f0[4], pf[4];
  #pragma unroll
  for (int ks = 0; ks < 4; ks++) f0[ks] = *(const uint4*)(fpp + ks*32);   // feat(t0)
  fpp += dstep;
  #pragma unroll
  for (int ks = 0; ks < 4; ks++) pf[ks] = *(const uint4*)(fpp + ks*32);   // feat(t0+1)
  fpp += dstep;
  // Final-step over-reads reach t0 +/- ~513 steps: fw lands in bufB's low MBs,
  // bw lands in bufA's high MBs — inside ws; values are dead.

  // prologue: ACCC = feat(t0)-part
  f32x4 accA[2], accB[2];
  accA[0] = MFMA16(*(const f16x8*)&f0[0], wg[0][0], zero4);
  accA[1] = MFMA16(*(const f16x8*)&f0[0], wg[1][0], zero4);
  #pragma unroll
  for (int ks = 1; ks < 4; ks++){
    accA[0] = MFMA16(*(const f16x8*)&f0[ks], wg[0][ks], accA[0]);
    accA[1] = MFMA16(*(const f16x8*)&f0[ks], wg[1][ks], accA[1]);
  }

  unsigned short* op = buf + ((size_t)t0*NB + n0 + lq*2)*128 + d*16 + lr;
  __syncthreads();   // init: hbS zeros visible (acts as step -1's barrier B)

  for (int s2 = 0; s2 < TN/2; s2++){
    LSTM_STEP(0, accA, accB);
    LSTM_STEP(1, accB, accA);
  }
}

// ---------------- K2: decoder (fp16 MFMA, K=256); inputs already relu'd ----------------
__global__ __launch_bounds__(256) void dec_kernel(
    const unsigned short* __restrict__ hfw, const unsigned short* __restrict__ hbw,
    const float* __restrict__ d1w, const float* __restrict__ d1b,
    const float* __restrict__ d2w, const float* __restrict__ d2b,
    float* __restrict__ out)
{
  __shared__ unsigned short A[64][264];  // [hfw||hbw], row stride 528B
  __shared__ float partial[4][64];
  int tid = threadIdx.x;
  long rowbase = (long)blockIdx.x * 64;
  #pragma unroll
  for (int u = 0; u < 8; u++){
    int chunk = u*256 + tid;             // 0..2047
    int row = chunk >> 5, seg = chunk & 31;
    const unsigned short* src = (seg < 16)
        ? (hfw + ((size_t)(rowbase + row))*128 + seg*8)
        : (hbw + ((size_t)(rowbase + row))*128 + (seg-16)*8);
    *(uint4*)&A[row][seg*8] = *(const uint4*)src;
  }
  int w4 = tid >> 6, lane = tid & 63, lq = lane >> 4, lr = lane & 15;
  f16x8 Bf[2][8];
  float b1v[2], w2v[2];
  #pragma unroll
  for (int nt2 = 0; nt2 < 2; nt2++){
    int col = (w4*2 + nt2)*16 + lr;
    b1v[nt2] = d1b[col];
    w2v[nt2] = d2w[col];
    #pragma unroll
    for (int ks = 0; ks < 8; ks++)
      Bf[nt2][ks] = cvt_frag(d1w + col*256 + ks*32 + lq*8);
  }
  float b2s = d2b[0];
  __syncthreads();
  #pragma unroll
  for (int Mt = 0; Mt < 4; Mt++){
    f16x8 ah[8];
    #pragma unroll
    for (int ks = 0; ks < 8; ks++)
      ah[ks] = *(const f16x8*)&A[Mt*16+lr][ks*32 + lq*8];
    f32x4 acc0 = {0.f,0.f,0.f,0.f}, acc1 = {0.f,0.f,0.f,0.f};
    #pragma unroll
    for (int ks = 0; ks < 8; ks++){
      acc0 = MFMA16(ah[ks], Bf[0][ks], acc0);
      acc1 = MFMA16(ah[ks], Bf[1][ks], acc1);
    }
    #pragma unroll
    for (int r = 0; r < 4; r++){
      float p = fmaxf(acc0[r] + b1v[0], 0.f) * w2v[0]
              + fmaxf(acc1[r] + b1v[1], 0.f) * w2v[1];
      p += __shfl_xor(p, 1);
      p += __shfl_xor(p, 2);
      p += __shfl_xor(p, 4);
      p += __shfl_xor(p, 8);
      if (lr == 0) partial[w4][Mt*16 + lq*4 + r] = p;
    }
  }
  __syncthreads();
  if (tid < 64){
    long row = rowbase + tid;
    int t = (int)(row >> 10), n = (int)(row & 1023);
    out[(size_t)n*TN + t] = partial[0][tid] + partial[1][tid]
                          + partial[2][tid] + partial[3][tid] + b2s;
  }
}

extern "C" void kernel_launch(void* const* d_in, const int* in_sizes, int n_in,
                              void* d_out, int out_size, void* d_ws, size_t ws_size,
                              hipStream_t stream)
{
  const float* x   = (const float*)d_in[0];
  const float* e1w = (const float*)d_in[1];
  const float* e1b = (const float*)d_in[2];
  const float* e2w = (const float*)d_in[3];
  const float* e2b = (const float*)d_in[4];
  const float* wih = (const float*)d_in[5];
  const float* whh = (const float*)d_in[6];
  const float* d1w = (const float*)d_in[7];
  const float* d1b = (const float*)d_in[8];
  const float* d2w = (const float*)d_in[9];
  const float* d2b = (const float*)d_in[10];
  float* out = (float*)d_out;

  if (ws_size < ((size_t)256 << 20)) return;   // ws guard (rounds 1-2 crashed on ws overflow)

  char* ws = (char*)d_ws;
  unsigned short* bufA = (unsigned short*)ws;                            // 128 MiB
  unsigned short* bufB = (unsigned short*)(ws + (((size_t)128) << 20));  // 128 MiB

  hipLaunchKernelGGL(enc_kernel, dim3(8192), dim3(256), 0, stream, x, e1w, e1b, e2w, e2b, bufA, bufB);
  hipLaunchKernelGGL(lstm_kernel, dim3(256), dim3(1024), 0, stream, bufA, bufB, wih, whh);
  hipLaunchKernelGGL(dec_kernel, dim3(8192), dim3(256), 0, stream, bufA, bufB, d1w, d1b, d2w, d2b, out);
}

// Round 15
// 703.245 us; speedup vs baseline: 1.3591x; 1.3591x over previous
//
#include <hip/hip_runtime.h>
#include <hip/hip_fp16.h>
#include <stdint.h>

// Bidirectional LSTM: N=1024, T=512, H=128; enc 2->128->128; dec 256->128->1.
// fp16 MFMA (fp32 accum). ws = 256 MiB:
//   bufA 128MiB: feat -> overwritten in place with relu(h_fw)   [t][n][128] fp16
//   bufB 128MiB: feat -> overwritten in place with relu(h_bw)   [t][n][128] fp16
// LSTM: 256 blocks x 512 thr, 8 samples/block (r7 structure, 495us best).
// Round-15: DEFERRED GLOBAL h-STORE. The compiler drains vmcnt(0) before each
// per-step s_barrier; r7 issued the h-stores immediately before the barrier ->
// ~300-900cy HBM write latency stalled every step (~530cy unexplained stall in
// the 2320cy budget). Now step t+1's TOP stores step t's h (carried packed in
// one VGPR); drain window = whole step. Step 0 stores a dummy (zeros) to the
// already-consumed feat(t0) row, overwritten by real h(t0) next step; epilogue
// stores the last h. Same values, same addresses -> absmax exact 2.441406e-4.

#define TN 512
#define NB 1024

typedef __attribute__((ext_vector_type(8))) _Float16 f16x8;
typedef __attribute__((ext_vector_type(4))) float f32x4;

#define MFMA16(a,b,c) __builtin_amdgcn_mfma_f32_16x16x32_f16(a,b,c,0,0,0)
#define RCP(x) __builtin_amdgcn_rcpf(x)

__device__ __forceinline__ f16x8 cvt_frag(const float* p){
  f32x4 a = *(const f32x4*)p;
  f32x4 b = *(const f32x4*)(p+4);
  f16x8 h;
  h[0]=(_Float16)a[0]; h[1]=(_Float16)a[1]; h[2]=(_Float16)a[2]; h[3]=(_Float16)a[3];
  h[4]=(_Float16)b[0]; h[5]=(_Float16)b[1]; h[6]=(_Float16)b[2]; h[7]=(_Float16)b[3];
  return h;
}

__device__ __forceinline__ unsigned short f2h(float f){
  return __half_as_ushort(__float2half(f));
}

// ---------------- K0: encoder -> feat fp16 [t][n][128], written to BOTH copies ----------------
__global__ __launch_bounds__(256) void enc_kernel(
    const float* __restrict__ x,  const float* __restrict__ e1w,
    const float* __restrict__ e1b,const float* __restrict__ e2w,
    const float* __restrict__ e2b,
    unsigned short* __restrict__ featA, unsigned short* __restrict__ featB)
{
  __shared__ float xs[64][2];
  __shared__ unsigned int A32[64][68];   // r1 fp16 pairs, row stride 272B
  int tid = threadIdx.x;
  long rowbase = (long)blockIdx.x * 64;  // row = t*1024 + n
  if (tid < 128){
    int i = tid >> 1, cc = tid & 1;
    long row = rowbase + i;
    int t = (int)(row >> 10), n = (int)(row & 1023);
    xs[i][cc] = x[((size_t)n * TN + t) * 2 + cc];
  }
  int w4 = tid >> 6, lane = tid & 63, lq = lane >> 4, lr = lane & 15;
  f16x8 Bf[2][4];
  float b2v[2];
  #pragma unroll
  for (int nt2 = 0; nt2 < 2; nt2++){
    int col = (w4*2 + nt2)*16 + lr;
    b2v[nt2] = e2b[col];
    #pragma unroll
    for (int ks = 0; ks < 4; ks++)
      Bf[nt2][ks] = cvt_frag(e2w + col*128 + ks*32 + lq*8);
  }
  int q = tid >> 6, dp = tid & 63;
  float w00 = e1w[4*dp], w01 = e1w[4*dp+1], w10 = e1w[4*dp+2], w11 = e1w[4*dp+3];
  float b0 = e1b[2*dp], b1 = e1b[2*dp+1];
  __syncthreads();
  #pragma unroll
  for (int rr = 0; rr < 16; rr++){
    int r = q*16 + rr;
    float x0 = xs[r][0], x1 = xs[r][1];
    float v0 = fmaxf(w00*x0 + w01*x1 + b0, 0.f);
    float v1 = fmaxf(w10*x0 + w11*x1 + b1, 0.f);
    A32[r][dp] = (unsigned int)f2h(v0) | ((unsigned int)f2h(v1) << 16);
  }
  __syncthreads();
  #pragma unroll
  for (int Mt = 0; Mt < 4; Mt++){
    f16x8 ah[4];
    #pragma unroll
    for (int ks = 0; ks < 4; ks++)
      ah[ks] = *(const f16x8*)((const unsigned short*)&A32[Mt*16+lr][0] + ks*32 + lq*8);
    f32x4 acc0 = {0.f,0.f,0.f,0.f}, acc1 = {0.f,0.f,0.f,0.f};
    #pragma unroll
    for (int ks = 0; ks < 4; ks++){
      acc0 = MFMA16(ah[ks], Bf[0][ks], acc0);
      acc1 = MFMA16(ah[ks], Bf[1][ks], acc1);
    }
    #pragma unroll
    for (int r = 0; r < 4; r++){
      size_t row = (size_t)(rowbase + Mt*16 + lq*4 + r);
      unsigned short v0 = f2h(acc0[r] + b2v[0]);
      unsigned short v1 = f2h(acc1[r] + b2v[1]);
      featA[row*128 + (w4*2+0)*16 + lr] = v0;
      featA[row*128 + (w4*2+1)*16 + lr] = v1;
      featB[row*128 + (w4*2+0)*16 + lr] = v0;
      featB[row*128 + (w4*2+1)*16 + lr] = v1;
    }
  }
}

// ---------------- K1: persistent bidirectional LSTM (deferred h-store) ----------------
// 256 blocks x 512 thr; block b: dir=b>>7, samples n0..n0+7.
// Wave w: gate tiles {i,f,g,o} for hidden dims [16w,16w+16); weights resident.
#define LSTM_STEP(P, PFC, PFN) do { \
    /* deferred store of PREVIOUS step's h (dummy zeros on very first step) */ \
    if (s2 > 0) op += dstep; \
    op[0]   = (unsigned short)(hc & 0xffffu); \
    op[128] = (unsigned short)(hc >> 16); \
    f16x8 ah[4]; \
    _Pragma("unroll") \
    for (int ks = 0; ks < 4; ks++) ah[ks] = *(const f16x8*)&hbS[P][smr][ks*32 + lq*8]; \
    _Pragma("unroll") \
    for (int ks = 0; ks < 4; ks++) PFN[ks] = *(const uint4*)(fpp + ks*32); \
    fpp += dstep; \
    f32x4 acc[4]; \
    _Pragma("unroll") \
    for (int G = 0; G < 4; G++) acc[G] = MFMA16(*(const f16x8*)&PFC[0], wg[G][0], zero4); \
    _Pragma("unroll") \
    for (int ks = 1; ks < 4; ks++){ \
      _Pragma("unroll") \
      for (int G = 0; G < 4; G++) acc[G] = MFMA16(*(const f16x8*)&PFC[ks], wg[G][ks], acc[G]); \
    } \
    _Pragma("unroll") \
    for (int ks = 0; ks < 4; ks++){ \
      _Pragma("unroll") \
      for (int G = 0; G < 4; G++) acc[G] = MFMA16(ah[ks], wg[G][4+ks], acc[G]); \
    } \
    _Pragma("unroll") \
    for (int r = 0; r < 2; r++){ \
      float iv = acc[0][r], fv = acc[1][r], gv = acc[2][r], ov = acc[3][r]; \
      float si = RCP(1.f + __expf(-iv)); \
      float sf = RCP(1.f + __expf(-fv)); \
      float so = RCP(1.f + __expf(-ov)); \
      float tg = 1.f - 2.f*RCP(__expf(2.f*gv) + 1.f); \
      c[r] = sf*c[r] + si*tg; \
      float tc = 1.f - 2.f*RCP(__expf(2.f*c[r]) + 1.f); \
      float hv = so*tc; \
      unsigned short hh = f2h(hv); \
      hbS[(P)^1][lq*2+r][w*16 + lr] = hh; \
      unsigned short rl = (hv > 0.f) ? hh : (unsigned short)0; \
      if (r == 0) hc = (unsigned int)rl; else hc |= ((unsigned int)rl) << 16; \
    } \
    __syncthreads(); \
  } while(0)

__global__ __launch_bounds__(512, 2) void lstm_kernel(
    unsigned short* bufA, unsigned short* bufB,
    const float* __restrict__ wih, const float* __restrict__ whh)
{
  __shared__ __align__(16) unsigned short hbS[2][8][136];   // h double-buffer, 4352 B
  int tid = threadIdx.x, b = blockIdx.x;
  int dir = b >> 7, n0 = (b & 127) << 3;
  int w = tid >> 6, lane = tid & 63, lq = lane >> 4, lr = lane & 15;
  unsigned short* buf = dir ? bufB : bufA;

  // resident fp16 weight fragments: k 0..127 = w_ih (feat), 128..255 = w_hh (h)
  f16x8 wg[4][8];
  #pragma unroll
  for (int G = 0; G < 4; G++){
    int gate = G*128 + w*16 + lr;
    #pragma unroll
    for (int ks = 0; ks < 8; ks++){
      const float* src = (ks < 4) ? (wih + (size_t)gate*128 + ks*32 + lq*8)
                                  : (whh + (size_t)gate*128 + (ks-4)*32 + lq*8);
      wg[G][ks] = cvt_frag(src);
    }
  }

  for (int i = tid; i < 1088; i += 512) ((unsigned int*)hbS)[i] = 0u;

  // A-row R carries sample ((R>>2)<<1)|(R&1); this lane reads A row lr.
  int smr = ((lr >> 2) << 1) | (lr & 1);
  float c[2] = {0.f, 0.f};
  const f32x4 zero4 = {0.f, 0.f, 0.f, 0.f};
  int t0 = dir ? (TN-1) : 0;
  long dstep = dir ? -(long)(NB*128) : (long)(NB*128);

  // running feat-prefetch pointer (this lane's A-row smr, k-chunk base lq*8)
  const unsigned short* fpp = buf + ((size_t)t0*NB + n0 + smr)*128 + lq*8;
  uint4 pfA[4], pfB[4];
  #pragma unroll
  for (int ks = 0; ks < 4; ks++) pfA[ks] = *(const uint4*)(fpp + ks*32);
  fpp += dstep;
  // Boundary over-reads on the final prefetches stay inside ws:
  //   fw: bufA + (512)*256KB == start of bufB; bw: bufB - 256KB == end of bufA.
  // Those loaded values are never consumed (loop ends first).

  // deferred-store state: op targets step (s-1)'s row at step s's top.
  // Step 0 stores dummy zeros to the t0 row (feat(t0) already consumed by the
  // prologue prefetch above; real h(t0) overwrites it at step 1's top).
  unsigned short* op = buf + ((size_t)t0*NB + n0 + lq*2)*128 + (w*16 + lr);
  unsigned int hc = 0;
  __syncthreads();

  for (int s2 = 0; s2 < TN/2; s2++){
    LSTM_STEP(0, pfA, pfB);
    LSTM_STEP(1, pfB, pfA);
  }
  // epilogue: store the final step's h
  op += dstep;
  op[0]   = (unsigned short)(hc & 0xffffu);
  op[128] = (unsigned short)(hc >> 16);
}

// ---------------- K2: decoder (fp16 MFMA, K=256); inputs already relu'd ----------------
__global__ __launch_bounds__(256) void dec_kernel(
    const unsigned short* __restrict__ hfw, const unsigned short* __restrict__ hbw,
    const float* __restrict__ d1w, const float* __restrict__ d1b,
    const float* __restrict__ d2w, const float* __restrict__ d2b,
    float* __restrict__ out)
{
  __shared__ unsigned short A[64][264];  // [hfw||hbw], row stride 528B
  __shared__ float partial[4][64];
  int tid = threadIdx.x;
  long rowbase = (long)blockIdx.x * 64;
  #pragma unroll
  for (int u = 0; u < 8; u++){
    int chunk = u*256 + tid;             // 0..2047
    int row = chunk >> 5, seg = chunk & 31;
    const unsigned short* src = (seg < 16)
        ? (hfw + ((size_t)(rowbase + row))*128 + seg*8)
        : (hbw + ((size_t)(rowbase + row))*128 + (seg-16)*8);
    *(uint4*)&A[row][seg*8] = *(const uint4*)src;
  }
  int w4 = tid >> 6, lane = tid & 63, lq = lane >> 4, lr = lane & 15;
  f16x8 Bf[2][8];
  float b1v[2], w2v[2];
  #pragma unroll
  for (int nt2 = 0; nt2 < 2; nt2++){
    int col = (w4*2 + nt2)*16 + lr;
    b1v[nt2] = d1b[col];
    w2v[nt2] = d2w[col];
    #pragma unroll
    for (int ks = 0; ks < 8; ks++)
      Bf[nt2][ks] = cvt_frag(d1w + col*256 + ks*32 + lq*8);
  }
  float b2s = d2b[0];
  __syncthreads();
  #pragma unroll
  for (int Mt = 0; Mt < 4; Mt++){
    f16x8 ah[8];
    #pragma unroll
    for (int ks = 0; ks < 8; ks++)
      ah[ks] = *(const f16x8*)&A[Mt*16+lr][ks*32 + lq*8];
    f32x4 acc0 = {0.f,0.f,0.f,0.f}, acc1 = {0.f,0.f,0.f,0.f};
    #pragma unroll
    for (int ks = 0; ks < 8; ks++){
      acc0 = MFMA16(ah[ks], Bf[0][ks], acc0);
      acc1 = MFMA16(ah[ks], Bf[1][ks], acc1);
    }
    #pragma unroll
    for (int r = 0; r < 4; r++){
      float p = fmaxf(acc0[r] + b1v[0], 0.f) * w2v[0]
              + fmaxf(acc1[r] + b1v[1], 0.f) * w2v[1];
      p += __shfl_xor(p, 1);
      p += __shfl_xor(p, 2);
      p += __shfl_xor(p, 4);
      p += __shfl_xor(p, 8);
      if (lr == 0) partial[w4][Mt*16 + lq*4 + r] = p;
    }
  }
  __syncthreads();
  if (tid < 64){
    long row = rowbase + tid;
    int t = (int)(row >> 10), n = (int)(row & 1023);
    out[(size_t)n*TN + t] = partial[0][tid] + partial[1][tid]
                          + partial[2][tid] + partial[3][tid] + b2s;
  }
}

extern "C" void kernel_launch(void* const* d_in, const int* in_sizes, int n_in,
                              void* d_out, int out_size, void* d_ws, size_t ws_size,
                              hipStream_t stream)
{
  const float* x   = (const float*)d_in[0];
  const float* e1w = (const float*)d_in[1];
  const float* e1b = (const float*)d_in[2];
  const float* e2w = (const float*)d_in[3];
  const float* e2b = (const float*)d_in[4];
  const float* wih = (const float*)d_in[5];
  const float* whh = (const float*)d_in[6];
  const float* d1w = (const float*)d_in[7];
  const float* d1b = (const float*)d_in[8];
  const float* d2w = (const float*)d_in[9];
  const float* d2b = (const float*)d_in[10];
  float* out = (float*)d_out;

  if (ws_size < ((size_t)256 << 20)) return;   // ws guard (rounds 1-2 crashed on ws overflow)

  char* ws = (char*)d_ws;
  unsigned short* bufA = (unsigned short*)ws;                            // 128 MiB
  unsigned short* bufB = (unsigned short*)(ws + (((size_t)128) << 20));  // 128 MiB

  hipLaunchKernelGGL(enc_kernel, dim3(8192), dim3(256), 0, stream, x, e1w, e1b, e2w, e2b, bufA, bufB);
  hipLaunchKernelGGL(lstm_kernel, dim3(256), dim3(512), 0, stream, bufA, bufB, wih, whh);
  hipLaunchKernelGGL(dec_kernel, dim3(8192), dim3(256), 0, stream, bufA, bufB, d1w, d1b, d2w, d2b, out);
}

// Round 16
// 631.012 us; speedup vs baseline: 1.5147x; 1.1145x over previous
//
#include <hip/hip_runtime.h>
#include <hip/hip_fp16.h>
#include <stdint.h>

// Bidirectional LSTM: N=1024, T=512, H=128; enc 2->128->128; dec 256->128->1.
// fp16 MFMA (fp32 accum). ws = 256 MiB:
//   bufA 128MiB: feat -> overwritten in place with relu(h_fw)   [t][n][128] fp16
//   bufB 128MiB: feat -> overwritten in place with relu(h_bw)   [t][n][128] fp16
// Round-16: LSTM reverted to r7 verbatim (best, 495us; 8 failed overlap
// attempts r8-r15 all reverted). enc: LDS repack -> coalesced uint4 stores
// (was 8 scalar 2B stores/thread). dec: 2048 blocks x 256 rows — d1w loaded/
// converted once per block instead of once per 64 rows (kills 1GB L2 traffic
// + redundant cvt VALU). All computed values bit-identical -> absmax oracle
// 2.441406e-4.

#define TN 512
#define NB 1024

typedef __attribute__((ext_vector_type(8))) _Float16 f16x8;
typedef __attribute__((ext_vector_type(4))) float f32x4;

#define MFMA16(a,b,c) __builtin_amdgcn_mfma_f32_16x16x32_f16(a,b,c,0,0,0)
#define RCP(x) __builtin_amdgcn_rcpf(x)

__device__ __forceinline__ f16x8 cvt_frag(const float* p){
  f32x4 a = *(const f32x4*)p;
  f32x4 b = *(const f32x4*)(p+4);
  f16x8 h;
  h[0]=(_Float16)a[0]; h[1]=(_Float16)a[1]; h[2]=(_Float16)a[2]; h[3]=(_Float16)a[3];
  h[4]=(_Float16)b[0]; h[5]=(_Float16)b[1]; h[6]=(_Float16)b[2]; h[7]=(_Float16)b[3];
  return h;
}

__device__ __forceinline__ unsigned short f2h(float f){
  return __half_as_ushort(__float2half(f));
}

// ---------------- K0: encoder -> feat fp16 [t][n][128], both copies, coalesced ----------------
__global__ __launch_bounds__(256) void enc_kernel(
    const float* __restrict__ x,  const float* __restrict__ e1w,
    const float* __restrict__ e1b,const float* __restrict__ e2w,
    const float* __restrict__ e2b,
    unsigned short* __restrict__ featA, unsigned short* __restrict__ featB)
{
  __shared__ float xs[64][2];
  __shared__ unsigned int A32[64][68];     // r1 fp16 pairs, row stride 272B
  __shared__ unsigned short A2[64][136];   // feat fp16 staging, row stride 272B
  int tid = threadIdx.x;
  long rowbase = (long)blockIdx.x * 64;  // row = t*1024 + n
  if (tid < 128){
    int i = tid >> 1, cc = tid & 1;
    long row = rowbase + i;
    int t = (int)(row >> 10), n = (int)(row & 1023);
    xs[i][cc] = x[((size_t)n * TN + t) * 2 + cc];
  }
  int w4 = tid >> 6, lane = tid & 63, lq = lane >> 4, lr = lane & 15;
  f16x8 Bf[2][4];
  float b2v[2];
  #pragma unroll
  for (int nt2 = 0; nt2 < 2; nt2++){
    int col = (w4*2 + nt2)*16 + lr;
    b2v[nt2] = e2b[col];
    #pragma unroll
    for (int ks = 0; ks < 4; ks++)
      Bf[nt2][ks] = cvt_frag(e2w + col*128 + ks*32 + lq*8);
  }
  int q = tid >> 6, dp = tid & 63;
  float w00 = e1w[4*dp], w01 = e1w[4*dp+1], w10 = e1w[4*dp+2], w11 = e1w[4*dp+3];
  float b0 = e1b[2*dp], b1 = e1b[2*dp+1];
  __syncthreads();
  #pragma unroll
  for (int rr = 0; rr < 16; rr++){
    int r = q*16 + rr;
    float x0 = xs[r][0], x1 = xs[r][1];
    float v0 = fmaxf(w00*x0 + w01*x1 + b0, 0.f);
    float v1 = fmaxf(w10*x0 + w11*x1 + b1, 0.f);
    A32[r][dp] = (unsigned int)f2h(v0) | ((unsigned int)f2h(v1) << 16);
  }
  __syncthreads();
  #pragma unroll
  for (int Mt = 0; Mt < 4; Mt++){
    f16x8 ah[4];
    #pragma unroll
    for (int ks = 0; ks < 4; ks++)
      ah[ks] = *(const f16x8*)((const unsigned short*)&A32[Mt*16+lr][0] + ks*32 + lq*8);
    f32x4 acc0 = {0.f,0.f,0.f,0.f}, acc1 = {0.f,0.f,0.f,0.f};
    #pragma unroll
    for (int ks = 0; ks < 4; ks++){
      acc0 = MFMA16(ah[ks], Bf[0][ks], acc0);
      acc1 = MFMA16(ah[ks], Bf[1][ks], acc1);
    }
    #pragma unroll
    for (int r = 0; r < 4; r++){
      int lrow = Mt*16 + lq*4 + r;
      A2[lrow][(w4*2+0)*16 + lr] = f2h(acc0[r] + b2v[0]);
      A2[lrow][(w4*2+1)*16 + lr] = f2h(acc1[r] + b2v[1]);
    }
  }
  __syncthreads();
  // coalesced stores: 64 rows x 128 fp16 = 1024 uint4 per buffer
  #pragma unroll
  for (int it = 0; it < 4; it++){
    int idx = it*256 + tid;            // 0..1023
    int row = idx >> 4, qq = idx & 15;
    uint4 v = *(const uint4*)&A2[row][qq*8];
    *(uint4*)(featA + ((size_t)(rowbase + row))*128 + qq*8) = v;
    *(uint4*)(featB + ((size_t)(rowbase + row))*128 + qq*8) = v;
  }
}

// ---------------- K1: persistent bidirectional LSTM (r7 verbatim — best) ----------------
// 256 blocks x 512 thr; block b: dir=b>>7, samples n0..n0+7.
// Wave w: gate tiles {i,f,g,o} for hidden dims [16w,16w+16); weights resident.
#define LSTM_STEP(P, PFC, PFN) do { \
    f16x8 ah[4]; \
    _Pragma("unroll") \
    for (int ks = 0; ks < 4; ks++) ah[ks] = *(const f16x8*)&hbS[P][smr][ks*32 + lq*8]; \
    _Pragma("unroll") \
    for (int ks = 0; ks < 4; ks++) PFN[ks] = *(const uint4*)(fpp + ks*32); \
    fpp += dstep; \
    f32x4 acc[4]; \
    _Pragma("unroll") \
    for (int G = 0; G < 4; G++) acc[G] = MFMA16(*(const f16x8*)&PFC[0], wg[G][0], zero4); \
    _Pragma("unroll") \
    for (int ks = 1; ks < 4; ks++){ \
      _Pragma("unroll") \
      for (int G = 0; G < 4; G++) acc[G] = MFMA16(*(const f16x8*)&PFC[ks], wg[G][ks], acc[G]); \
    } \
    _Pragma("unroll") \
    for (int ks = 0; ks < 4; ks++){ \
      _Pragma("unroll") \
      for (int G = 0; G < 4; G++) acc[G] = MFMA16(ah[ks], wg[G][4+ks], acc[G]); \
    } \
    _Pragma("unroll") \
    for (int r = 0; r < 2; r++){ \
      float iv = acc[0][r], fv = acc[1][r], gv = acc[2][r], ov = acc[3][r]; \
      float si = RCP(1.f + __expf(-iv)); \
      float sf = RCP(1.f + __expf(-fv)); \
      float so = RCP(1.f + __expf(-ov)); \
      float tg = 1.f - 2.f*RCP(__expf(2.f*gv) + 1.f); \
      c[r] = sf*c[r] + si*tg; \
      float tc = 1.f - 2.f*RCP(__expf(2.f*c[r]) + 1.f); \
      float hv = so*tc; \
      unsigned short hh = f2h(hv); \
      hbS[(P)^1][lq*2+r][w*16 + lr] = hh; \
      op[r*128] = (hv > 0.f) ? hh : (unsigned short)0; \
    } \
    op += dstep; \
    __syncthreads(); \
  } while(0)

__global__ __launch_bounds__(512, 2) void lstm_kernel(
    unsigned short* bufA, unsigned short* bufB,
    const float* __restrict__ wih, const float* __restrict__ whh)
{
  __shared__ __align__(16) unsigned short hbS[2][8][136];   // h double-buffer, 4352 B
  int tid = threadIdx.x, b = blockIdx.x;
  int dir = b >> 7, n0 = (b & 127) << 3;
  int w = tid >> 6, lane = tid & 63, lq = lane >> 4, lr = lane & 15;
  unsigned short* buf = dir ? bufB : bufA;

  // resident fp16 weight fragments: k 0..127 = w_ih (feat), 128..255 = w_hh (h)
  f16x8 wg[4][8];
  #pragma unroll
  for (int G = 0; G < 4; G++){
    int gate = G*128 + w*16 + lr;
    #pragma unroll
    for (int ks = 0; ks < 8; ks++){
      const float* src = (ks < 4) ? (wih + (size_t)gate*128 + ks*32 + lq*8)
                                  : (whh + (size_t)gate*128 + (ks-4)*32 + lq*8);
      wg[G][ks] = cvt_frag(src);
    }
  }

  for (int i = tid; i < 1088; i += 512) ((unsigned int*)hbS)[i] = 0u;

  // A-row R carries sample ((R>>2)<<1)|(R&1); this lane reads A row lr.
  int smr = ((lr >> 2) << 1) | (lr & 1);
  float c[2] = {0.f, 0.f};
  const f32x4 zero4 = {0.f, 0.f, 0.f, 0.f};
  int t0 = dir ? (TN-1) : 0;
  long dstep = dir ? -(long)(NB*128) : (long)(NB*128);

  // running feat-prefetch pointer (this lane's A-row smr, k-chunk base lq*8)
  const unsigned short* fpp = buf + ((size_t)t0*NB + n0 + smr)*128 + lq*8;
  uint4 pfA[4], pfB[4];
  #pragma unroll
  for (int ks = 0; ks < 4; ks++) pfA[ks] = *(const uint4*)(fpp + ks*32);
  fpp += dstep;
  // Boundary over-reads on the final prefetches stay inside ws:
  //   fw: bufA + (512)*256KB == start of bufB; bw: bufB - 256KB == end of bufA.
  // Those loaded values are never consumed (loop ends first).

  // running output pointer: sample lq*2 (+1 via imm offset 128), dim w*16+lr
  unsigned short* op = buf + ((size_t)t0*NB + n0 + lq*2)*128 + (w*16 + lr);
  __syncthreads();

  for (int s2 = 0; s2 < TN/2; s2++){
    LSTM_STEP(0, pfA, pfB);
    LSTM_STEP(1, pfB, pfA);
  }
}

// ---------------- K2: decoder (fp16 MFMA, K=256); 2048 blocks x 256 rows ----------------
__global__ __launch_bounds__(256) void dec_kernel(
    const unsigned short* __restrict__ hfw, const unsigned short* __restrict__ hbw,
    const float* __restrict__ d1w, const float* __restrict__ d1b,
    const float* __restrict__ d2w, const float* __restrict__ d2b,
    float* __restrict__ out)
{
  __shared__ unsigned short A[64][264];  // [hfw||hbw], row stride 528B
  __shared__ float partial[4][64];
  int tid = threadIdx.x;
  int w4 = tid >> 6, lane = tid & 63, lq = lane >> 4, lr = lane & 15;
  // weights loaded & converted ONCE per block (amortized over 256 rows)
  f16x8 Bf[2][8];
  float b1v[2], w2v[2];
  #pragma unroll
  for (int nt2 = 0; nt2 < 2; nt2++){
    int col = (w4*2 + nt2)*16 + lr;
    b1v[nt2] = d1b[col];
    w2v[nt2] = d2w[col];
    #pragma unroll
    for (int ks = 0; ks < 8; ks++)
      Bf[nt2][ks] = cvt_frag(d1w + col*256 + ks*32 + lq*8);
  }
  float b2s = d2b[0];

  for (int ch = 0; ch < 4; ch++){
    long rowbase = (long)blockIdx.x * 256 + ch * 64;
    #pragma unroll
    for (int u = 0; u < 8; u++){
      int chunk = u*256 + tid;             // 0..2047
      int row = chunk >> 5, seg = chunk & 31;
      const unsigned short* src = (seg < 16)
          ? (hfw + ((size_t)(rowbase + row))*128 + seg*8)
          : (hbw + ((size_t)(rowbase + row))*128 + (seg-16)*8);
      *(uint4*)&A[row][seg*8] = *(const uint4*)src;
    }
    __syncthreads();    // A visible (and prev chunk's partial reads done)
    #pragma unroll
    for (int Mt = 0; Mt < 4; Mt++){
      f16x8 ah[8];
      #pragma unroll
      for (int ks = 0; ks < 8; ks++)
        ah[ks] = *(const f16x8*)&A[Mt*16+lr][ks*32 + lq*8];
      f32x4 acc0 = {0.f,0.f,0.f,0.f}, acc1 = {0.f,0.f,0.f,0.f};
      #pragma unroll
      for (int ks = 0; ks < 8; ks++){
        acc0 = MFMA16(ah[ks], Bf[0][ks], acc0);
        acc1 = MFMA16(ah[ks], Bf[1][ks], acc1);
      }
      #pragma unroll
      for (int r = 0; r < 4; r++){
        float p = fmaxf(acc0[r] + b1v[0], 0.f) * w2v[0]
                + fmaxf(acc1[r] + b1v[1], 0.f) * w2v[1];
        p += __shfl_xor(p, 1);
        p += __shfl_xor(p, 2);
        p += __shfl_xor(p, 4);
        p += __shfl_xor(p, 8);
        if (lr == 0) partial[w4][Mt*16 + lq*4 + r] = p;
      }
    }
    __syncthreads();    // partial visible; all A reads complete
    if (tid < 64){
      long row = rowbase + tid;
      int t = (int)(row >> 10), n = (int)(row & 1023);
      out[(size_t)n*TN + t] = partial[0][tid] + partial[1][tid]
                            + partial[2][tid] + partial[3][tid] + b2s;
    }
  }
}

extern "C" void kernel_launch(void* const* d_in, const int* in_sizes, int n_in,
                              void* d_out, int out_size, void* d_ws, size_t ws_size,
                              hipStream_t stream)
{
  const float* x   = (const float*)d_in[0];
  const float* e1w = (const float*)d_in[1];
  const float* e1b = (const float*)d_in[2];
  const float* e2w = (const float*)d_in[3];
  const float* e2b = (const float*)d_in[4];
  const float* wih = (const float*)d_in[5];
  const float* whh = (const float*)d_in[6];
  const float* d1w = (const float*)d_in[7];
  const float* d1b = (const float*)d_in[8];
  const float* d2w = (const float*)d_in[9];
  const float* d2b = (const float*)d_in[10];
  float* out = (float*)d_out;

  if (ws_size < ((size_t)256 << 20)) return;   // ws guard (rounds 1-2 crashed on ws overflow)

  char* ws = (char*)d_ws;
  unsigned short* bufA = (unsigned short*)ws;                            // 128 MiB
  unsigned short* bufB = (unsigned short*)(ws + (((size_t)128) << 20));  // 128 MiB

  hipLaunchKernelGGL(enc_kernel, dim3(8192), dim3(256), 0, stream, x, e1w, e1b, e2w, e2b, bufA, bufB);
  hipLaunchKernelGGL(lstm_kernel, dim3(256), dim3(512), 0, stream, bufA, bufB, wih, whh);
  hipLaunchKernelGGL(dec_kernel, dim3(2048), dim3(256), 0, stream, bufA, bufB, d1w, d1b, d2w, d2b, out);
}

// Round 17
// 618.777 us; speedup vs baseline: 1.5447x; 1.0198x over previous
//
#include <hip/hip_runtime.h>
#include <hip/hip_fp16.h>
#include <stdint.h>

// Bidirectional LSTM: N=1024, T=512, H=128; enc 2->128->128; dec 256->128->1.
// fp16 MFMA (fp32 accum). ws = 256 MiB:
//   bufA 128MiB: feat -> overwritten in place with relu(h_fw)   [t][n][128] fp16
//   bufB 128MiB: feat -> overwritten in place with relu(h_bw)   [t][n][128] fp16
// Round-17 LSTM: 2-step feat batching. A/C row R = 2*chain + stepofs (full 16
// rows, zero M-waste on the feat part): 16 feat-MFMAs per 2-step window (was
// 32). h-part runs per step over the same C-tile with the inactive step's
// A-rows PRE-ZEROED in LDS: Z1 = h in even rows / odd rows always 0 (read by
// pass 1), Z2 = mirror (read by pass 2). Zero rows contribute exactly 0 ->
// bit-exact. 24 MFMA/wave/step (was 32). Barriers: 2/window = 1/step, and they
// separate all Z read/write hazards. Per-value FP op order identical to r7 ->
// absmax oracle 2.441406e-4. enc/dec: r16 versions (coalesced / amortized).

#define TN 512
#define NB 1024

typedef __attribute__((ext_vector_type(8))) _Float16 f16x8;
typedef __attribute__((ext_vector_type(4))) float f32x4;

#define MFMA16(a,b,c) __builtin_amdgcn_mfma_f32_16x16x32_f16(a,b,c,0,0,0)
#define RCP(x) __builtin_amdgcn_rcpf(x)

__device__ __forceinline__ f16x8 cvt_frag(const float* p){
  f32x4 a = *(const f32x4*)p;
  f32x4 b = *(const f32x4*)(p+4);
  f16x8 h;
  h[0]=(_Float16)a[0]; h[1]=(_Float16)a[1]; h[2]=(_Float16)a[2]; h[3]=(_Float16)a[3];
  h[4]=(_Float16)b[0]; h[5]=(_Float16)b[1]; h[6]=(_Float16)b[2]; h[7]=(_Float16)b[3];
  return h;
}

__device__ __forceinline__ unsigned short f2h(float f){
  return __half_as_ushort(__float2half(f));
}

// ---------------- K0: encoder -> feat fp16 [t][n][128], both copies, coalesced ----------------
__global__ __launch_bounds__(256) void enc_kernel(
    const float* __restrict__ x,  const float* __restrict__ e1w,
    const float* __restrict__ e1b,const float* __restrict__ e2w,
    const float* __restrict__ e2b,
    unsigned short* __restrict__ featA, unsigned short* __restrict__ featB)
{
  __shared__ float xs[64][2];
  __shared__ unsigned int A32[64][68];     // r1 fp16 pairs, row stride 272B
  __shared__ unsigned short A2[64][136];   // feat fp16 staging, row stride 272B
  int tid = threadIdx.x;
  long rowbase = (long)blockIdx.x * 64;  // row = t*1024 + n
  if (tid < 128){
    int i = tid >> 1, cc = tid & 1;
    long row = rowbase + i;
    int t = (int)(row >> 10), n = (int)(row & 1023);
    xs[i][cc] = x[((size_t)n * TN + t) * 2 + cc];
  }
  int w4 = tid >> 6, lane = tid & 63, lq = lane >> 4, lr = lane & 15;
  f16x8 Bf[2][4];
  float b2v[2];
  #pragma unroll
  for (int nt2 = 0; nt2 < 2; nt2++){
    int col = (w4*2 + nt2)*16 + lr;
    b2v[nt2] = e2b[col];
    #pragma unroll
    for (int ks = 0; ks < 4; ks++)
      Bf[nt2][ks] = cvt_frag(e2w + col*128 + ks*32 + lq*8);
  }
  int q = tid >> 6, dp = tid & 63;
  float w00 = e1w[4*dp], w01 = e1w[4*dp+1], w10 = e1w[4*dp+2], w11 = e1w[4*dp+3];
  float b0 = e1b[2*dp], b1 = e1b[2*dp+1];
  __syncthreads();
  #pragma unroll
  for (int rr = 0; rr < 16; rr++){
    int r = q*16 + rr;
    float x0 = xs[r][0], x1 = xs[r][1];
    float v0 = fmaxf(w00*x0 + w01*x1 + b0, 0.f);
    float v1 = fmaxf(w10*x0 + w11*x1 + b1, 0.f);
    A32[r][dp] = (unsigned int)f2h(v0) | ((unsigned int)f2h(v1) << 16);
  }
  __syncthreads();
  #pragma unroll
  for (int Mt = 0; Mt < 4; Mt++){
    f16x8 ah[4];
    #pragma unroll
    for (int ks = 0; ks < 4; ks++)
      ah[ks] = *(const f16x8*)((const unsigned short*)&A32[Mt*16+lr][0] + ks*32 + lq*8);
    f32x4 acc0 = {0.f,0.f,0.f,0.f}, acc1 = {0.f,0.f,0.f,0.f};
    #pragma unroll
    for (int ks = 0; ks < 4; ks++){
      acc0 = MFMA16(ah[ks], Bf[0][ks], acc0);
      acc1 = MFMA16(ah[ks], Bf[1][ks], acc1);
    }
    #pragma unroll
    for (int r = 0; r < 4; r++){
      int lrow = Mt*16 + lq*4 + r;
      A2[lrow][(w4*2+0)*16 + lr] = f2h(acc0[r] + b2v[0]);
      A2[lrow][(w4*2+1)*16 + lr] = f2h(acc1[r] + b2v[1]);
    }
  }
  __syncthreads();
  #pragma unroll
  for (int it = 0; it < 4; it++){
    int idx = it*256 + tid;            // 0..1023
    int row = idx >> 4, qq = idx & 15;
    uint4 v = *(const uint4*)&A2[row][qq*8];
    *(uint4*)(featA + ((size_t)(rowbase + row))*128 + qq*8) = v;
    *(uint4*)(featB + ((size_t)(rowbase + row))*128 + qq*8) = v;
  }
}

// ---------------- K1: persistent bidirectional LSTM (2-step feat batching) ----------------
// 256 blocks x 512 thr; block b: dir=b>>7, chains n0..n0+7.
// A/C row R = 2*chain + so. Lane owns C rows lq*4+r: r={0,2} = step-even for
// chains {2lq, 2lq+1}; r={1,3} = step-odd. Wave w: gates {i,f,g,o} at dims
// [16w,16w+16). Elementwise per value identical to r7.
#define LSTM_EW(RA, RB, ZW, RO) do { \
    float iv0=acc[0][RA], fv0=acc[1][RA], gv0=acc[2][RA], ov0=acc[3][RA]; \
    float si0 = RCP(1.f + __expf(-iv0)); \
    float sf0 = RCP(1.f + __expf(-fv0)); \
    float so0 = RCP(1.f + __expf(-ov0)); \
    float tg0 = 1.f - 2.f*RCP(__expf(2.f*gv0) + 1.f); \
    c[0] = sf0*c[0] + si0*tg0; \
    float tc0 = 1.f - 2.f*RCP(__expf(2.f*c[0]) + 1.f); \
    float hv0 = so0*tc0; \
    float iv1=acc[0][RB], fv1=acc[1][RB], gv1=acc[2][RB], ov1=acc[3][RB]; \
    float si1 = RCP(1.f + __expf(-iv1)); \
    float sf1 = RCP(1.f + __expf(-fv1)); \
    float so1 = RCP(1.f + __expf(-ov1)); \
    float tg1 = 1.f - 2.f*RCP(__expf(2.f*gv1) + 1.f); \
    c[1] = sf1*c[1] + si1*tg1; \
    float tc1 = 1.f - 2.f*RCP(__expf(2.f*c[1]) + 1.f); \
    float hv1 = so1*tc1; \
    unsigned short hh0 = f2h(hv0), hh1 = f2h(hv1); \
    ZW[4*lq + (RO)][w*16 + lr]     = hh0; \
    ZW[4*lq + 2 + (RO)][w*16 + lr] = hh1; \
    op[0]   = (hv0 > 0.f) ? hh0 : (unsigned short)0; \
    op[128] = (hv1 > 0.f) ? hh1 : (unsigned short)0; \
    op += dstep; \
  } while(0)

#define LSTM_WINDOW(PFC, PFN) do { \
    _Pragma("unroll") \
    for (int ks = 0; ks < 4; ks++) PFN[ks] = *(const uint4*)(fpp + ks*32); \
    fpp += 2*dstep; \
    f32x4 acc[4]; \
    _Pragma("unroll") \
    for (int G = 0; G < 4; G++) acc[G] = MFMA16(*(const f16x8*)&PFC[0], wf[G][0], zero4); \
    _Pragma("unroll") \
    for (int ks = 1; ks < 4; ks++){ \
      _Pragma("unroll") \
      for (int G = 0; G < 4; G++) acc[G] = MFMA16(*(const f16x8*)&PFC[ks], wf[G][ks], acc[G]); \
    } \
    { /* pass 1: h(s-1) from Z1 (odd rows are permanent zeros) */ \
      f16x8 ah[4]; \
      _Pragma("unroll") \
      for (int ks = 0; ks < 4; ks++) ah[ks] = *(const f16x8*)&Z[0][lr][ks*32 + lq*8]; \
      _Pragma("unroll") \
      for (int ks = 0; ks < 4; ks++){ \
        _Pragma("unroll") \
        for (int G = 0; G < 4; G++) acc[G] = MFMA16(ah[ks], wh[G][ks], acc[G]); \
      } \
    } \
    LSTM_EW(0, 2, Z[1], 1);   /* even step: rows 4lq+1, 4lq+3 of Z2 */ \
    __syncthreads();          /* A: Z2 h-rows visible; Z1 reads done */ \
    { /* pass 2: h(s) from Z2 (even rows are permanent zeros) */ \
      f16x8 ah[4]; \
      _Pragma("unroll") \
      for (int ks = 0; ks < 4; ks++) ah[ks] = *(const f16x8*)&Z[1][lr][ks*32 + lq*8]; \
      _Pragma("unroll") \
      for (int ks = 0; ks < 4; ks++){ \
        _Pragma("unroll") \
        for (int G = 0; G < 4; G++) acc[G] = MFMA16(ah[ks], wh[G][ks], acc[G]); \
      } \
    } \
    LSTM_EW(1, 3, Z[0], 0);   /* odd step: rows 4lq, 4lq+2 of Z1 */ \
    __syncthreads();          /* B: Z1 h-rows visible; Z2 reads done */ \
  } while(0)

__global__ __launch_bounds__(512, 2) void lstm_kernel(
    unsigned short* bufA, unsigned short* bufB,
    const float* __restrict__ wih, const float* __restrict__ whh)
{
  // Z[0]=Z1: h in even rows (written by odd-step EW), odd rows always 0.
  // Z[1]=Z2: h in odd rows (written by even-step EW), even rows always 0.
  __shared__ __align__(16) unsigned short Z[2][16][136];   // 8704 B
  int tid = threadIdx.x, b = blockIdx.x;
  int dir = b >> 7, n0 = (b & 127) << 3;
  int w = tid >> 6, lane = tid & 63, lq = lane >> 4, lr = lane & 15;
  unsigned short* buf = dir ? bufB : bufA;

  // resident fp16 weight fragments: wf = w_ih (feat part), wh = w_hh (h part)
  f16x8 wf[4][4], wh[4][4];
  #pragma unroll
  for (int G = 0; G < 4; G++){
    int gate = G*128 + w*16 + lr;
    #pragma unroll
    for (int ks = 0; ks < 4; ks++){
      wf[G][ks] = cvt_frag(wih + (size_t)gate*128 + ks*32 + lq*8);
      wh[G][ks] = cvt_frag(whh + (size_t)gate*128 + ks*32 + lq*8);
    }
  }

  for (int i = tid; i < 2176; i += 512) ((unsigned int*)Z)[i] = 0u;

  float c[2] = {0.f, 0.f};
  const f32x4 zero4 = {0.f, 0.f, 0.f, 0.f};
  int t0 = dir ? (TN-1) : 0;
  long dstep = dir ? -(long)(NB*128) : (long)(NB*128);

  // feat A-row lr = (chain lr>>1, step-ofs lr&1); window stride = 2 steps
  const unsigned short* fpp = buf + ((size_t)t0*NB + n0 + (lr >> 1))*128
                            + (long)(lr & 1)*dstep + lq*8;
  uint4 pfA[4], pfB[4];
  #pragma unroll
  for (int ks = 0; ks < 4; ks++) pfA[ks] = *(const uint4*)(fpp + ks*32);   // window 0
  fpp += 2*dstep;
  // Boundary over-reads (last window prefetches t0 +/- 512..513) stay inside
  // ws: fw lands at bufB's start rows, bw at bufA's end rows; values dead.

  // output pointer: chains 2lq (+1 via offset 128), dim w*16+lr; +=dstep per EW
  unsigned short* op = buf + ((size_t)t0*NB + n0 + lq*2)*128 + (w*16 + lr);
  __syncthreads();

  for (int wd = 0; wd < 128; wd++){
    LSTM_WINDOW(pfA, pfB);
    LSTM_WINDOW(pfB, pfA);
  }
}

// ---------------- K2: decoder (fp16 MFMA, K=256); 2048 blocks x 256 rows ----------------
__global__ __launch_bounds__(256) void dec_kernel(
    const unsigned short* __restrict__ hfw, const unsigned short* __restrict__ hbw,
    const float* __restrict__ d1w, const float* __restrict__ d1b,
    const float* __restrict__ d2w, const float* __restrict__ d2b,
    float* __restrict__ out)
{
  __shared__ unsigned short A[64][264];  // [hfw||hbw], row stride 528B
  __shared__ float partial[4][64];
  int tid = threadIdx.x;
  int w4 = tid >> 6, lane = tid & 63, lq = lane >> 4, lr = lane & 15;
  f16x8 Bf[2][8];
  float b1v[2], w2v[2];
  #pragma unroll
  for (int nt2 = 0; nt2 < 2; nt2++){
    int col = (w4*2 + nt2)*16 + lr;
    b1v[nt2] = d1b[col];
    w2v[nt2] = d2w[col];
    #pragma unroll
    for (int ks = 0; ks < 8; ks++)
      Bf[nt2][ks] = cvt_frag(d1w + col*256 + ks*32 + lq*8);
  }
  float b2s = d2b[0];

  for (int ch = 0; ch < 4; ch++){
    long rowbase = (long)blockIdx.x * 256 + ch * 64;
    #pragma unroll
    for (int u = 0; u < 8; u++){
      int chunk = u*256 + tid;             // 0..2047
      int row = chunk >> 5, seg = chunk & 31;
      const unsigned short* src = (seg < 16)
          ? (hfw + ((size_t)(rowbase + row))*128 + seg*8)
          : (hbw + ((size_t)(rowbase + row))*128 + (seg-16)*8);
      *(uint4*)&A[row][seg*8] = *(const uint4*)src;
    }
    __syncthreads();
    #pragma unroll
    for (int Mt = 0; Mt < 4; Mt++){
      f16x8 ah[8];
      #pragma unroll
      for (int ks = 0; ks < 8; ks++)
        ah[ks] = *(const f16x8*)&A[Mt*16+lr][ks*32 + lq*8];
      f32x4 acc0 = {0.f,0.f,0.f,0.f}, acc1 = {0.f,0.f,0.f,0.f};
      #pragma unroll
      for (int ks = 0; ks < 8; ks++){
        acc0 = MFMA16(ah[ks], Bf[0][ks], acc0);
        acc1 = MFMA16(ah[ks], Bf[1][ks], acc1);
      }
      #pragma unroll
      for (int r = 0; r < 4; r++){
        float p = fmaxf(acc0[r] + b1v[0], 0.f) * w2v[0]
                + fmaxf(acc1[r] + b1v[1], 0.f) * w2v[1];
        p += __shfl_xor(p, 1);
        p += __shfl_xor(p, 2);
        p += __shfl_xor(p, 4);
        p += __shfl_xor(p, 8);
        if (lr == 0) partial[w4][Mt*16 + lq*4 + r] = p;
      }
    }
    __syncthreads();
    if (tid < 64){
      long row = rowbase + tid;
      int t = (int)(row >> 10), n = (int)(row & 1023);
      out[(size_t)n*TN + t] = partial[0][tid] + partial[1][tid]
                            + partial[2][tid] + partial[3][tid] + b2s;
    }
  }
}

extern "C" void kernel_launch(void* const* d_in, const int* in_sizes, int n_in,
                              void* d_out, int out_size, void* d_ws, size_t ws_size,
                              hipStream_t stream)
{
  const float* x   = (const float*)d_in[0];
  const float* e1w = (const float*)d_in[1];
  const float* e1b = (const float*)d_in[2];
  const float* e2w = (const float*)d_in[3];
  const float* e2b = (const float*)d_in[4];
  const float* wih = (const float*)d_in[5];
  const float* whh = (const float*)d_in[6];
  const float* d1w = (const float*)d_in[7];
  const float* d1b = (const float*)d_in[8];
  const float* d2w = (const float*)d_in[9];
  const float* d2b = (const float*)d_in[10];
  float* out = (float*)d_out;

  if (ws_size < ((size_t)256 << 20)) return;   // ws guard (rounds 1-2 crashed on ws overflow)

  char* ws = (char*)d_ws;
  unsigned short* bufA = (unsigned short*)ws;                            // 128 MiB
  unsigned short* bufB = (unsigned short*)(ws + (((size_t)128) << 20));  // 128 MiB

  hipLaunchKernelGGL(enc_kernel, dim3(8192), dim3(256), 0, stream, x, e1w, e1b, e2w, e2b, bufA, bufB);
  hipLaunchKernelGGL(lstm_kernel, dim3(256), dim3(512), 0, stream, bufA, bufB, wih, whh);
  hipLaunchKernelGGL(dec_kernel, dim3(2048), dim3(256), 0, stream, bufA, bufB, d1w, d1b, d2w, d2b, out);
}